// Round 7
// baseline (84.281 us; speedup 1.0000x reference)
//
#include <hip/hip_runtime.h>
#include <math.h>

typedef unsigned int u32;
typedef unsigned long long u64;

#define N_ELEM 131072
#define NBIN 16384         // 14-bit key-space bins
#define BSH 18             // key >> 18 -> bin
#define CAP 2048           // candidate capacity per array (typ. ~25 used)
#define SCAN_CAP 64        // max bins scanned upward in successor proof
#define GMARG 0.0999       // conservative gap margin (< 0.1*(1-1e-9))
#define GRID 64            // persistent blocks (128 KB LDS -> 1/CU, co-resident on 256 CUs)
#define NBA 32             // data blocks per array
#define EPB 4096           // elements per block in data phases

// ascending-sortable key: monotone bijection f32 -> u32
__device__ __forceinline__ u32 kasc(float x) {
  u32 u = __float_as_uint(x);
  return (u & 0x80000000u) ? ~u : (u | 0x80000000u);
}
__device__ __forceinline__ float kasc2f(u32 t) {
  return __uint_as_float((t & 0x80000000u) ? (t ^ 0x80000000u) : ~t);
}

// device-scope grid barrier (cg grid.sync protocol: release-fence, arrive,
// coherent-point spin, acquire-fence). Counters zeroed by hipMemsetAsync
// before every launch (graph replays the memset too -> no cross-call state).
__device__ __forceinline__ void gbar(u32* bars, int idx) {
  __syncthreads();
  if (threadIdx.x == 0) {
    __threadfence();                      // release: XCD-L2 writeback
    atomicAdd(&bars[idx], 1u);
    while (atomicAdd(&bars[idx], 0u) < (u32)GRID) __builtin_amdgcn_s_sleep(2);
    __threadfence();                      // acquire: cache invalidate
  }
  __syncthreads();
}

__global__ __launch_bounds__(256) void k_mega(
    const float* __restrict__ in0, const float* __restrict__ in1,
    u32* binMinK, u32* binMaxK, u32* candCnt, float* candVal,
    u32* pCnt, double* pSum, float* segV, double* segS, int* segN,
    double* part, u32* bars, float* out) {
  __shared__ union {
    struct { u32 lmn[NBIN]; u32 lmx[NBIN]; } h;                      // 128 KB
    struct { float lv[EPB]; } ps;                                    // 16 KB
    struct { int sp[CAP]; float svv[CAP]; int dp[CAP]; float dv[CAP];
             double scv[CAP]; double dc[CAP]; int ntop; } hu;        // 64 KB
    struct { float lv0[CAP]; float lv1[CAP];
             double ls0[CAP]; double ls1[CAP];
             double s0[256]; double s1[256]; double s2[256]; } rm;   // 54 KB
  } S;
  const int blk = blockIdx.x, t = threadIdx.x;
  const int arr = blk >> 5, b = blk & 31;
  const float* pin = arr ? in1 : in0;

  // ---- phase A: init global bins + candidate counters ----
  for (int i = blk * 256 + t; i < 2 * NBIN; i += GRID * 256) {
    binMinK[i] = 0xFFFFFFFFu;
    binMaxK[i] = 0u;
  }
  if (blk == 0 && t < 2) candCnt[t] = 0u;
  gbar(bars, 0);

  // ---- phase B: exact per-bin min/max keys (LDS-staged; nonempty <=> min!=~0) ----
  for (int k = t; k < NBIN; k += 256) { S.h.lmn[k] = 0xFFFFFFFFu; S.h.lmx[k] = 0u; }
  __syncthreads();
  {
    const float4* p4 = (const float4*)(pin + b * EPB);
#pragma unroll
    for (int q = 0; q < 4; q++) {
      float4 v = p4[t + 256 * q];
      float xs[4] = {v.x, v.y, v.z, v.w};
#pragma unroll
      for (int e = 0; e < 4; e++) {
        u32 k = kasc(xs[e]);
        u32 bin = k >> BSH;
        atomicMin(&S.h.lmn[bin], k);   // LDS atomics: order-independent
        atomicMax(&S.h.lmx[bin], k);
      }
    }
  }
  __syncthreads();
  {
    u32* bmn = binMinK + arr * NBIN;
    u32* bmx = binMaxK + arr * NBIN;
    for (int k = t; k < NBIN; k += 256) {
      u32 mn = S.h.lmn[k];
      if (mn != 0xFFFFFFFFu) {         // flush nonempty bins only
        atomicMin(&bmn[k], mn);
        atomicMax(&bmx[k], S.h.lmx[k]);
      }
    }
  }
  gbar(bars, 1);

  // ---- phase C: candidate detection ----
  // Flag x unless we can PROVE an element exists in (x, x+GMARG] (then the
  // sorted gap above x's run is < reg -> x cannot be a hull vertex). Proof
  // sources (exact keys): own-bin max, or first nonempty higher bin's min.
  // Over-inclusion safe: flagged v yields a valid diagram point (p, C[p]);
  // the exact f64 hull (phase E) discards non-vertices.
  {
    const u32* bmn = binMinK + arr * NBIN;
    const u32* bmx = binMaxK + arr * NBIN;
    if (b == 0 && t == 0) {  // right-endpoint sentinel: p = N
      u32 s = atomicAdd(&candCnt[arr], 1u);
      if (s < CAP) candVal[arr * CAP + s] = -INFINITY;
    }
    const float4* p4 = (const float4*)(pin + b * EPB);
    for (int q = 0; q < 4; q++) {
      float4 v4 = p4[t + 256 * q];
      float xs[4] = {v4.x, v4.y, v4.z, v4.w};
      for (int e = 0; e < 4; e++) {
        float x = xs[e];
        double xd = (double)x;
        u32 k = kasc(x);
        u32 bn = k >> BSH;
        bool proven = false, decided = false;
        u32 mx = bmx[bn];
        if (mx > k) {  // someone strictly above me in my own bin
          proven = ((double)kasc2f(mx) - xd <= GMARG);
          decided = true;
        }
        if (!decided) {
          for (int it = 0; it < SCAN_CAP; it++) {
            bn++;
            if (bn >= NBIN) break;
            double lb = (double)kasc2f(bn << BSH);
            if (lb > xd + GMARG) break;
            u32 mn = bmn[bn];
            if (mn != 0xFFFFFFFFu) {
              proven = ((double)kasc2f(mn) - xd <= GMARG);
              break;
            }
          }
        }
        if (!proven) {
          u32 s = atomicAdd(&candCnt[arr], 1u);
          if (s < CAP) candVal[arr * CAP + s] = x;
        }
      }
    }
  }
  gbar(bars, 2);

  // ---- phase D: per-block masked count/sum per candidate threshold ----
  {
#pragma unroll
    for (int q = 0; q < 4; q++)
      ((float4*)S.ps.lv)[t + 256 * q] = ((const float4*)(pin + b * EPB))[t + 256 * q];
    __syncthreads();
    int lane = t & 63, w = t >> 6;
    u32 cc = candCnt[arr];
    int cnt = (int)(cc < (u32)CAP ? cc : (u32)CAP);
    for (int j = w; j < cnt; j += 4) {
      float v = candVal[arr * CAP + j];
      int c = 0;
      double s = 0.0;
      for (int e = lane; e < EPB; e += 64) {
        float x = S.ps.lv[e];
        if (x > v) { c++; s += (double)x; }
      }
#pragma unroll
      for (int o = 32; o > 0; o >>= 1) {
        c += __shfl_down(c, o);
        s += __shfl_down(s, o);
      }
      if (lane == 0) {
        pCnt[((size_t)(arr * NBA + b)) * CAP + j] = (u32)c;
        pSum[((size_t)(arr * NBA + b)) * CAP + j] = s;
      }
    }
  }
  gbar(bars, 3);

  // ---- phase E: reduce partials -> (p, C[p]); sort by p; monotone chain ----
  if (blk < 2) {
    int a2 = blk;
    u32 cc = candCnt[a2];
    int cnt = (int)(cc < (u32)CAP ? cc : (u32)CAP);
    for (int j = t; j < cnt; j += 256) {
      long long c = 0;
      double s = 0.0;
      for (int bb = 0; bb < NBA; bb++) {  // fixed order -> deterministic
        c += (long long)pCnt[((size_t)(a2 * NBA + bb)) * CAP + j];
        s += pSum[((size_t)(a2 * NBA + bb)) * CAP + j];
      }
      double pd = (double)c;
      // C[p] = S_p/reg - (p*n - p(p-1)/2), exact in f64
      S.hu.sp[j] = (int)c;
      S.hu.scv[j] = s / 0.1 - (pd * (double)N_ELEM - pd * (pd - 1.0) * 0.5);
      S.hu.svv[j] = candVal[a2 * CAP + j];
    }
    __syncthreads();
    // rank sort by (p, j); equal-p records have identical (p,C) and their value
    // choice provably cannot change segment classification -> deterministic out
    for (int j = t; j < cnt; j += 256) {
      int pj = S.hu.sp[j], rk = 0;
      for (int k = 0; k < cnt; k++) {
        int pk = S.hu.sp[k];
        rk += (pk < pj) || (pk == pj && k < j);
      }
      S.hu.dp[rk] = pj; S.hu.dc[rk] = S.hu.scv[j]; S.hu.dv[rk] = S.hu.svv[j];
    }
    __syncthreads();
    if (t == 0) {
      int top = 0, aX = 0, bX = 0, prevP = -1;
      double cA = 0.0, cB = 0.0;
      for (int k = 0; k < cnt; k++) {
        int i = S.hu.dp[k];
        if (i == prevP) continue;  // dedupe identical diagram points
        prevP = i;
        double Ci = S.hu.dc[k];
        float vi = S.hu.dv[k];
        while (top >= 2) {
          double cr = (double)(bX - aX) * (Ci - cA) - (cB - cA) * (double)(i - aX);
          if (cr >= 0.0) {  // bX on/below chord aX->i : pop
            top--;
            bX = aX; cB = cA;
            if (top >= 2) { aX = S.hu.dp[top - 2]; cA = S.hu.dc[top - 2]; }
          } else break;
        }
        S.hu.dp[top] = i; S.hu.dc[top] = Ci; S.hu.dv[top] = vi;
        aX = bX; cA = cB;
        bX = i;  cB = Ci;
        top++;
      }
      S.hu.ntop = top;
    }
    __syncthreads();
    int top = S.hu.ntop;
    for (int k = t; k < top - 1; k += 256) {
      segV[a2 * CAP + k] = S.hu.dv[k];  // left-vertex value (descending)
      segS[a2 * CAP + k] = (S.hu.dc[k + 1] - S.hu.dc[k]) / (double)(S.hu.dp[k + 1] - S.hu.dp[k]);
    }
    if (t == 0) segN[a2] = top - 1;
  }
  gbar(bars, 4);

  // ---- phase F: fused rank + centered moments ----
  // x in segment k iff v_k >= x > v_{k+1}; rank = x/reg - slope_k. Mean is
  // analytic: permutahedron projection preserves sum -> mean = (N+1)/2.
  {
    int n0 = segN[0], n1 = segN[1];
    for (int k = t; k < n0; k += 256) { S.rm.lv0[k] = segV[k]; S.rm.ls0[k] = segS[k]; }
    for (int k = t; k < n1; k += 256) { S.rm.lv1[k] = segV[CAP + k]; S.rm.ls1[k] = segS[CAP + k]; }
    __syncthreads();
    const double m = 0.5 * (double)(N_ELEM + 1);  // 65536.5
    double a0 = 0.0, a1 = 0.0, a2 = 0.0;
    const float4* q0 = (const float4*)(in0 + blk * 2048);
    const float4* q1 = (const float4*)(in1 + blk * 2048);
#pragma unroll
    for (int q = 0; q < 2; q++) {
      float4 x4 = q0[t + 256 * q], y4 = q1[t + 256 * q];
      float xs[4] = {x4.x, x4.y, x4.z, x4.w};
      float ys[4] = {y4.x, y4.y, y4.z, y4.w};
#pragma unroll
      for (int e = 0; e < 4; e++) {
        float x = xs[e], y = ys[e];
        int k0 = 0, k1 = 0;
        for (int k = 1; k < n0; k++) if (x <= S.rm.lv0[k]) k0 = k;
        for (int k = 1; k < n1; k++) if (y <= S.rm.lv1[k]) k1 = k;
        double ra = (double)x / 0.1 - S.rm.ls0[k0] - m;
        double rb = (double)y / 0.1 - S.rm.ls1[k1] - m;
        a0 += ra * rb;
        a1 += ra * ra;
        a2 += rb * rb;
      }
    }
    S.rm.s0[t] = a0; S.rm.s1[t] = a1; S.rm.s2[t] = a2;
    __syncthreads();
    for (int off = 128; off > 0; off >>= 1) {
      if (t < off) {
        S.rm.s0[t] += S.rm.s0[t + off];
        S.rm.s1[t] += S.rm.s1[t + off];
        S.rm.s2[t] += S.rm.s2[t + off];
      }
      __syncthreads();
    }
    if (t == 0) {
      part[blk] = S.rm.s0[0];
      part[GRID + blk] = S.rm.s1[0];
      part[2 * GRID + blk] = S.rm.s2[0];
    }
  }
  gbar(bars, 5);

  // ---- phase G: final reduction (one wave) ----
  if (blk == 0 && t < 64) {
    double v0 = part[t], v1 = part[GRID + t], v2 = part[2 * GRID + t];
#pragma unroll
    for (int off = 32; off > 0; off >>= 1) {
      v0 += __shfl_down(v0, off);
      v1 += __shfl_down(v1, off);
      v2 += __shfl_down(v2, off);
    }
    if (t == 0) out[0] = (float)(v0 / (sqrt(v1) * sqrt(v2)));
  }
}

// ---------------- host ----------------
extern "C" void kernel_launch(void* const* d_in, const int* in_sizes, int n_in,
                              void* d_out, int out_size, void* d_ws, size_t ws_size,
                              hipStream_t stream) {
  const float* in0 = (const float*)d_in[0];
  const float* in1 = (const float*)d_in[1];
  float* out = (float*)d_out;

  size_t off = 0;
  char* base = (char*)d_ws;
  auto alloc = [&](size_t bytes) -> char* {
    char* p = base + off;
    off += (bytes + 63) & ~(size_t)63;
    return p;
  };
  u32* binMinK = (u32*)alloc(sizeof(u32) * 2 * NBIN);
  u32* binMaxK = (u32*)alloc(sizeof(u32) * 2 * NBIN);
  u32* candCnt = (u32*)alloc(sizeof(u32) * 2);
  float* candVal = (float*)alloc(sizeof(float) * 2 * CAP);
  u32* pCnt    = (u32*)alloc(sizeof(u32) * 2 * NBA * CAP);
  double* pSum = (double*)alloc(sizeof(double) * 2 * NBA * CAP);
  float* segV  = (float*)alloc(sizeof(float) * 2 * CAP);
  double* segS = (double*)alloc(sizeof(double) * 2 * CAP);
  int* segN    = (int*)alloc(sizeof(int) * 2);
  double* part = (double*)alloc(sizeof(double) * 3 * GRID);
  u32* bars    = (u32*)alloc(sizeof(u32) * 16);
  (void)ws_size; (void)in_sizes; (void)n_in; (void)out_size;

  // zero the barrier counters (replayed in the graph every iteration)
  hipMemsetAsync(bars, 0, sizeof(u32) * 16, stream);

  k_mega<<<dim3(GRID), dim3(256), 0, stream>>>(
      in0, in1, binMinK, binMaxK, candCnt, candVal,
      pCnt, pSum, segV, segS, segN, part, bars, out);
}